// Round 15
// baseline (271.827 us; speedup 1.0000x reference)
//
#include <hip/hip_runtime.h>

#define DEV static __device__ __forceinline__

typedef __bf16 bf16x8 __attribute__((ext_vector_type(8)));
typedef __bf16 bf16x4 __attribute__((ext_vector_type(4)));
typedef float  f32x4  __attribute__((ext_vector_type(4)));

DEV bf16x8 ld8(const __bf16* p) { return *reinterpret_cast<const bf16x8*>(p); }

DEV f32x4 mfma16(bf16x8 a, bf16x8 b, f32x4 c) {
  return __builtin_amdgcn_mfma_f32_16x16x32_bf16(a, b, c, 0, 0, 0);
}

// B=2, S=2048, D=768, H=12, HD=64
#define SEQ 2048
#define DIM 768
#define NH  12
#define HDIM 64

// chunk decode for 128-row q-tiles: q-tile qt has 2*qt+2 k-tiles (64 cols).
DEV void decode_chunk2(int cid, int CH, int& qt, int& t0) {
  int q = 0, rem = cid;
  while (true) {
    int nc = (2 * q + 2 + CH - 1) / CH;
    if (rem < nc) break;
    rem -= nc; ++q;
  }
  qt = q; t0 = rem * CH;
}

// chunk decode for 256-row super-tiles, CH=4: super-tile st has 4*st+4
// k-tiles -> st+1 chunks of 4.
DEV void decode_chunk4(int cid, int& st, int& t0) {
  int q = 0, rem = cid;
  while (rem >= q + 1) { rem -= q + 1; ++q; }
  st = q; t0 = rem * 4;
}

// ---------------------------------------------------------------------------
// prep_misc: fused zero(AOf+sums) and cvt(x->bf16). grid 2560 x 256.
// ---------------------------------------------------------------------------
__global__ __launch_bounds__(256) void prep_misc(const float* __restrict__ x,
                                                 __bf16* __restrict__ xb,
                                                 float* __restrict__ zp) {
  const int bid = blockIdx.x, tid = threadIdx.x;
  if (bid < 1024) {
    const int n4 = (3145728 + 49152) / 4;
    const f32x4 zv = {0.f, 0.f, 0.f, 0.f};
    for (int i = bid * 256 + tid; i < n4; i += 1024 * 256) ((f32x4*)zp)[i] = zv;
  } else {
    const int i = ((bid - 1024) * 256 + tid) * 8;
    f32x4 a = *(const f32x4*)(x + i);
    f32x4 b = *(const f32x4*)(x + i + 4);
    bf16x8 v;
    #pragma unroll
    for (int j = 0; j < 4; ++j) { v[j] = (__bf16)a[j]; v[4 + j] = (__bf16)b[j]; }
    *(bf16x8*)(xb + i) = v;
  }
}

// ---------------------------------------------------------------------------
// prep_wt: transpose+convert the 4 weight matrices to bf16 [out_n][in_k].
// ---------------------------------------------------------------------------
__global__ __launch_bounds__(256) void prep_wt(
    const float* __restrict__ Wq, const float* __restrict__ Wk,
    const float* __restrict__ Wv, const float* __restrict__ Wo,
    __bf16* __restrict__ WbT) {
  __shared__ float T[64][65];
  const int z = blockIdx.z;
  const float* W = (z == 0) ? Wq : (z == 1) ? Wk : (z == 2) ? Wv : Wo;
  const int kb = blockIdx.x * 64, nb = blockIdx.y * 64;
  const int t = threadIdx.x, r = t >> 2, c4 = (t & 3) * 16;
  #pragma unroll
  for (int j = 0; j < 16; j += 4) {
    f32x4 v = *(const f32x4*)(W + (size_t)(kb + r) * DIM + nb + c4 + j);
    T[r][c4 + j]     = v[0]; T[r][c4 + j + 1] = v[1];
    T[r][c4 + j + 2] = v[2]; T[r][c4 + j + 3] = v[3];
  }
  __syncthreads();
  bf16x8 o0, o1;
  #pragma unroll
  for (int j = 0; j < 8; ++j) {
    o0[j] = (__bf16)T[c4 + j][r];
    o1[j] = (__bf16)T[c4 + 8 + j][r];
  }
  __bf16* dst = WbT + (size_t)z * DIM * DIM + (size_t)(nb + r) * DIM + kb + c4;
  *(bf16x8*)dst = o0;
  *(bf16x8*)(dst + 8) = o1;
}

// ---------------------------------------------------------------------------
// gemm128: C[128x128 tile], 4 waves 2x2, each 64x64 via 4x4 frags, BK=64.
// LDS rows padded to 72 bf16 (144B stride) -> 2-way max bank aliasing.
// ---------------------------------------------------------------------------
DEV void gemm128(const __bf16* __restrict__ Ab, const __bf16* __restrict__ Bt,
                 const float* __restrict__ bias, void* __restrict__ outp,
                 const int mode, const float scale,
                 const int mbase, const int nbase) {
  __shared__ __bf16 As[128][72];
  __shared__ __bf16 Bs[128][72];

  const int tid  = threadIdx.x;
  const int l    = tid & 63;
  const int w    = tid >> 6;
  const int lrow = l & 15;
  const int lk8  = (l >> 4) * 8;
  const int wr = (w >> 1) * 64, wc = (w & 1) * 64;

  f32x4 acc[4][4] = {};

  const int srow = tid >> 1;          // 0..127
  const int scol = (tid & 1) * 32;    // 0 or 32 (bf16 elems)

  for (int kk = 0; kk < DIM; kk += 64) {
    {
      const __bf16* a = Ab + (size_t)(mbase + srow) * DIM + kk + scol;
      *(bf16x8*)&As[srow][scol]      = ld8(a);
      *(bf16x8*)&As[srow][scol + 8]  = ld8(a + 8);
      *(bf16x8*)&As[srow][scol + 16] = ld8(a + 16);
      *(bf16x8*)&As[srow][scol + 24] = ld8(a + 24);
    }
    {
      const __bf16* b = Bt + (size_t)(nbase + srow) * DIM + kk + scol;
      *(bf16x8*)&Bs[srow][scol]      = ld8(b);
      *(bf16x8*)&Bs[srow][scol + 8]  = ld8(b + 8);
      *(bf16x8*)&Bs[srow][scol + 16] = ld8(b + 16);
      *(bf16x8*)&Bs[srow][scol + 24] = ld8(b + 24);
    }
    __syncthreads();
    #pragma unroll
    for (int kc = 0; kc < 2; ++kc) {
      bf16x8 af[4], bf[4];
      #pragma unroll
      for (int mi = 0; mi < 4; ++mi)
        af[mi] = ld8(&As[wr + mi * 16 + lrow][kc * 32 + lk8]);
      #pragma unroll
      for (int ni = 0; ni < 4; ++ni)
        bf[ni] = ld8(&Bs[wc + ni * 16 + lrow][kc * 32 + lk8]);
      #pragma unroll
      for (int mi = 0; mi < 4; ++mi)
        #pragma unroll
        for (int ni = 0; ni < 4; ++ni)
          acc[mi][ni] = mfma16(af[mi], bf[ni], acc[mi][ni]);
    }
    __syncthreads();
  }

  #pragma unroll
  for (int mi = 0; mi < 4; ++mi)
  #pragma unroll
  for (int ni = 0; ni < 4; ++ni) {
    const int n  = nbase + wc + ni * 16 + lrow;
    const float bn = bias[n];
    const int hh = n >> 6, hd = n & 63;
    #pragma unroll
    for (int r = 0; r < 4; ++r) {
      const int m = mbase + wr + mi * 16 + (l >> 4) * 4 + r;
      const float v = (acc[mi][ni][r] + bn) * scale;
      const int bb = m >> 11, s = m & (SEQ - 1);
      if (mode == 0) {
        ((__bf16*)outp)[(((size_t)(bb * NH + hh) * SEQ) + s) * HDIM + hd] = (__bf16)v;
      } else {
        ((__bf16*)outp)[(((size_t)(bb * NH + hh) * HDIM) + hd) * SEQ + s] = (__bf16)v;
      }
    }
  }
}

__global__ __launch_bounds__(256, 2) void qkv_gemm(
    const __bf16* __restrict__ xb, const __bf16* __restrict__ WbT,
    const float* __restrict__ bq, const float* __restrict__ bk,
    const float* __restrict__ bv,
    __bf16* __restrict__ Qb, __bf16* __restrict__ Kb, __bf16* __restrict__ Vt) {
  const int z = blockIdx.z;
  const __bf16* Bt = WbT + (size_t)z * DIM * DIM;
  const float* bs = (z == 0) ? bq : (z == 1) ? bk : bv;
  void* o = (z == 0) ? (void*)Qb : (z == 1) ? (void*)Kb : (void*)Vt;
  const float sc = (z == 0) ? 0.125f : 1.f;  // fold 1/sqrt(HD) into Q
  gemm128(xb, Bt, bs, o, (z == 2) ? 1 : 0, sc,
          blockIdx.y * 128, blockIdx.x * 128);
}

// ---------------------------------------------------------------------------
// out_gemm: 64x64-tile GEMM, fp32 A (AOf), fp32 out. grid (12,64).
// ---------------------------------------------------------------------------
__global__ __launch_bounds__(256, 4) void out_gemm(
    const float* __restrict__ Af, const __bf16* __restrict__ WbT,
    const float* __restrict__ bias, float* __restrict__ out) {
  __shared__ __bf16 As[64][72];
  __shared__ __bf16 Bs[64][72];

  const __bf16* Bt = WbT + (size_t)3 * DIM * DIM;
  const int mbase = blockIdx.y * 64, nbase = blockIdx.x * 64;
  const int tid  = threadIdx.x;
  const int l    = tid & 63;
  const int w    = tid >> 6;
  const int lrow = l & 15;
  const int lk8  = (l >> 4) * 8;
  const int wrow = (w >> 1) * 32, wcol = (w & 1) * 32;

  f32x4 acc[2][2] = {};

  const int arow = tid >> 2;
  const int acol = (tid & 3) * 16;

  for (int kk = 0; kk < DIM; kk += 64) {
    {
      const float* src = Af + (size_t)(mbase + arow) * DIM + kk + acol;
      f32x4 f0 = *(const f32x4*)(src);
      f32x4 f1 = *(const f32x4*)(src + 4);
      f32x4 f2 = *(const f32x4*)(src + 8);
      f32x4 f3 = *(const f32x4*)(src + 12);
      bf16x8 v0, v1;
      #pragma unroll
      for (int j = 0; j < 4; ++j) {
        v0[j] = (__bf16)f0[j]; v0[4 + j] = (__bf16)f1[j];
        v1[j] = (__bf16)f2[j]; v1[4 + j] = (__bf16)f3[j];
      }
      *(bf16x8*)&As[arow][acol]     = v0;
      *(bf16x8*)&As[arow][acol + 8] = v1;
    }
    {
      const __bf16* bsrc = Bt + (size_t)(nbase + arow) * DIM + kk + acol;
      *(bf16x8*)&Bs[arow][acol]     = ld8(bsrc);
      *(bf16x8*)&Bs[arow][acol + 8] = ld8(bsrc + 8);
    }
    __syncthreads();
    #pragma unroll
    for (int kc = 0; kc < 2; ++kc) {
      bf16x8 a0 = ld8(&As[wrow + lrow][kc * 32 + lk8]);
      bf16x8 a1 = ld8(&As[wrow + 16 + lrow][kc * 32 + lk8]);
      bf16x8 b0 = ld8(&Bs[wcol + lrow][kc * 32 + lk8]);
      bf16x8 b1 = ld8(&Bs[wcol + 16 + lrow][kc * 32 + lk8]);
      acc[0][0] = mfma16(a0, b0, acc[0][0]);
      acc[0][1] = mfma16(a0, b1, acc[0][1]);
      acc[1][0] = mfma16(a1, b0, acc[1][0]);
      acc[1][1] = mfma16(a1, b1, acc[1][1]);
    }
    __syncthreads();
  }

  #pragma unroll
  for (int mi = 0; mi < 2; ++mi)
  #pragma unroll
  for (int ni = 0; ni < 2; ++ni) {
    const int n  = nbase + wcol + ni * 16 + lrow;
    const float bn = bias[n];
    #pragma unroll
    for (int r = 0; r < 4; ++r) {
      const int m = mbase + wrow + mi * 16 + (l >> 4) * 4 + r;
      out[(size_t)m * DIM + n] = acc[mi][ni][r] + bn;
    }
  }
}

// ---------------------------------------------------------------------------
// attn_sums: swapped-operand QK^T, 4 q-frags/wave over 256-row super-tiles.
// Fused zero-fill: full-width reflected tiles t<4st, PLUS half-width strip
// for t in {4st,4st+1} cols [256st+128, 256st+256) -- closes the hole left
// by wpv's 128-row tiles (qt=2st covers cols only to 256st+128).
// grid = 8*3*36 = 864 blocks.
// ---------------------------------------------------------------------------
__global__ __launch_bounds__(256, 4) void attn_sums(
    const __bf16* __restrict__ Q, const __bf16* __restrict__ K,
    float* __restrict__ sums, float* __restrict__ Wout) {
  const int tid = threadIdx.x, l = tid & 63, w = tid >> 6;
  const int lrow = l & 15, lk8 = (l >> 4) * 8, g = l >> 4;
  const int lin = blockIdx.x;
  const int C = 36;
  const int bh = (lin & 7) * 3 + (lin >> 3) / C;
  const int cid = (lin >> 3) % C;
  int st, t0; decode_chunk4(cid, st, t0);
  const int tmax = 4 * st + 4;
  const int t1 = (t0 + 4 < tmax) ? t0 + 4 : tmax;

  const __bf16* Qh = Q + (size_t)bh * SEQ * HDIM;
  const __bf16* Kh = K + (size_t)bh * SEQ * HDIM;

  int fb[4];
  bf16x8 bq0[4], bq1[4];
  #pragma unroll
  for (int i = 0; i < 4; ++i) {
    fb[i] = st * 256 + w * 64 + i * 16;
    const int q = fb[i] + lrow;
    bq0[i] = ld8(Qh + (size_t)q * HDIM + lk8);
    bq1[i] = ld8(Qh + (size_t)q * HDIM + 32 + lk8);
  }

  float ssum[4] = {0.f, 0.f, 0.f, 0.f};
  for (int t = t0; t < t1; ++t) {
    const int kb = t * 64;
    if (kb > fb[3] + 15) continue;  // above all 4 frags
    #pragma unroll
    for (int nt = 0; nt < 4; ++nt) {
      const int krow = kb + nt * 16 + lrow;
      const bf16x8 ak0 = ld8(Kh + (size_t)krow * HDIM + lk8);
      const bf16x8 ak1 = ld8(Kh + (size_t)krow * HDIM + 32 + lk8);
      const int k0 = kb + nt * 16 + g * 4;
      #pragma unroll
      for (int i = 0; i < 4; ++i) {
        if (kb <= fb[i] + 15) {  // frag live (wave-uniform)
          f32x4 s0 = {0.f, 0.f, 0.f, 0.f}, s1 = {0.f, 0.f, 0.f, 0.f};
          s0 = mfma16(ak0, bq0[i], s0);
          s1 = mfma16(ak1, bq1[i], s1);
          const int q = fb[i] + lrow;
          if (kb + 63 <= fb[i]) {
            #pragma unroll
            for (int r = 0; r < 4; ++r) ssum[i] += __expf(s0[r] + s1[r]);
          } else {
            #pragma unroll
            for (int r = 0; r < 4; ++r)
              ssum[i] += (k0 + r <= q) ? __expf(s0[r] + s1[r]) : 0.f;
          }
        }
      }
    }
  }
  #pragma unroll
  for (int i = 0; i < 4; ++i) {
    ssum[i] += __shfl_xor(ssum[i], 16);
    ssum[i] += __shfl_xor(ssum[i], 32);
  }
  if (g == 0) {
    #pragma unroll
    for (int i = 0; i < 4; ++i)
      unsafeAtomicAdd(&sums[bh * SEQ + fb[i] + lrow], ssum[i]);
  }

  float* Wg = Wout + (size_t)bh * SEQ * SEQ;
  const f32x4 zv = {0.f, 0.f, 0.f, 0.f};
  // ---- full-width reflected fill: t in [t0, min(t1, 4*st)) ----
  const int tz = (t1 < 4 * st) ? t1 : 4 * st;
  if (t0 < tz) {
    const int zr = tid >> 2;             // 0..63
    const int zc = (tid & 3) * 64;       // 0,64,128,192 floats
    for (int t = t0; t < tz; ++t) {
      float* base = Wg + (size_t)(t * 64 + zr) * SEQ + st * 256 + zc;
      #pragma unroll
      for (int c = 0; c < 16; ++c) *(f32x4*)(base + c * 4) = zv;
    }
  }
  // ---- half-width hole fill: t in [max(t0,4st), min(t1,4st+2)),
  //      cols [st*256+128, st*256+256) (wpv qt=2st stops at col 256st+128) --
  const int ta = (t0 > 4 * st) ? t0 : 4 * st;
  const int tb = (t1 < 4 * st + 2) ? t1 : 4 * st + 2;
  if (ta < tb) {
    const int zr = tid >> 2;
    const int zc = (tid & 3) * 32;       // 0,32,64,96 floats (128 total)
    for (int t = ta; t < tb; ++t) {
      float* base = Wg + (size_t)(t * 64 + zr) * SEQ + st * 256 + 128 + zc;
      #pragma unroll
      for (int c = 0; c < 8; ++c) *(f32x4*)(base + c * 4) = zv;
    }
  }
}

// ---------------------------------------------------------------------------
// attn_wpv: swapped-operand QK^T, 2 q-frags/wave; f32x4 Wg stores direct from
// registers; P converted to bf16 BEFORE LDS staging (8B ds_write, ld8 read
// feeds PV MFMA directly; in-wave RAW, no barriers); atomicAdd AOf.
// grid = 8*3*40 = 960 blocks.
// ---------------------------------------------------------------------------
__global__ __launch_bounds__(256, 4) void attn_wpv(
    const __bf16* __restrict__ Q, const __bf16* __restrict__ K,
    const __bf16* __restrict__ VT, const float* __restrict__ sums,
    float* __restrict__ Wout, float* __restrict__ AOf) {
  __shared__ __bf16 Plds[4][2][16][72];

  const int tid = threadIdx.x, l = tid & 63, w = tid >> 6;
  const int lrow = l & 15, lk8 = (l >> 4) * 8, g = l >> 4;
  const int lin = blockIdx.x;
  const int C = 40;
  const int bh = (lin & 7) * 3 + (lin >> 3) / C;
  const int cid = (lin >> 3) % C;
  int qt, t0; decode_chunk2(cid, 8, qt, t0);
  const int tmax = 2 * qt + 2;
  const int t1 = (t0 + 8 < tmax) ? t0 + 8 : tmax;
  const int bb = bh / NH, hh = bh % NH;
  const int fb0 = qt * 128 + w * 32;
  const int fb1 = fb0 + 16;
  const int q0 = fb0 + lrow, q1 = fb1 + lrow;

  const __bf16* Qh = Q + (size_t)bh * SEQ * HDIM;
  const __bf16* Kh = K + (size_t)bh * SEQ * HDIM;
  const __bf16* Vh = VT + (size_t)bh * HDIM * SEQ;
  float* Wg = Wout + (size_t)bh * SEQ * SEQ;

  const bf16x8 bqA0 = ld8(Qh + (size_t)q0 * HDIM + lk8);
  const bf16x8 bqA1 = ld8(Qh + (size_t)q0 * HDIM + 32 + lk8);
  const bf16x8 bqB0 = ld8(Qh + (size_t)q1 * HDIM + lk8);
  const bf16x8 bqB1 = ld8(Qh + (size_t)q1 * HDIM + 32 + lk8);
  const float invA = 1.f / sums[bh * SEQ + q0];
  const float invB = 1.f / sums[bh * SEQ + q1];

  f32x4 accA[4] = {}, accB[4] = {};
  for (int t = t0; t < t1; ++t) {
    const int kb = t * 64;
    const bool liveA = (kb <= fb0 + 15);
    const bool liveB = (kb <= fb1 + 15);
    const f32x4 zv = {0.f, 0.f, 0.f, 0.f};
    if (!liveB) {
      #pragma unroll
      for (int nt = 0; nt < 4; ++nt) {
        const int k0 = kb + nt * 16 + g * 4;
        *(f32x4*)&Wg[(size_t)q0 * SEQ + k0] = zv;
        *(f32x4*)&Wg[(size_t)q1 * SEQ + k0] = zv;
      }
      continue;
    }
    #pragma unroll
    for (int nt = 0; nt < 4; ++nt) {
      const int krow = kb + nt * 16 + lrow;
      const bf16x8 ak0 = ld8(Kh + (size_t)krow * HDIM + lk8);
      const bf16x8 ak1 = ld8(Kh + (size_t)krow * HDIM + 32 + lk8);
      const int k0 = kb + nt * 16 + g * 4;
      f32x4 pvA = zv;
      if (liveA) {
        f32x4 s0 = {0.f, 0.f, 0.f, 0.f}, s1 = {0.f, 0.f, 0.f, 0.f};
        s0 = mfma16(ak0, bqA0, s0);
        s1 = mfma16(ak1, bqA1, s1);
        if (kb + 63 <= fb0) {
          #pragma unroll
          for (int r = 0; r < 4; ++r) pvA[r] = __expf(s0[r] + s1[r]) * invA;
        } else {
          #pragma unroll
          for (int r = 0; r < 4; ++r)
            pvA[r] = (k0 + r <= q0) ? __expf(s0[r] + s1[r]) * invA : 0.f;
        }
        bf16x4 pb;
        #pragma unroll
        for (int r = 0; r < 4; ++r) pb[r] = (__bf16)pvA[r];
        *(bf16x4*)&Plds[w][0][lrow][nt * 16 + g * 4] = pb;
      }
      *(f32x4*)&Wg[(size_t)q0 * SEQ + k0] = pvA;
      f32x4 pvB;
      {
        f32x4 s0 = {0.f, 0.f, 0.f, 0.f}, s1 = {0.f, 0.f, 0.f, 0.f};
        s0 = mfma16(ak0, bqB0, s0);
        s1 = mfma16(ak1, bqB1, s1);
        if (kb + 63 <= fb1) {
          #pragma unroll
          for (int r = 0; r < 4; ++r) pvB[r] = __expf(s0[r] + s1[r]) * invB;
        } else {
          #pragma unroll
          for (int r = 0; r < 4; ++r)
            pvB[r] = (k0 + r <= q1) ? __expf(s0[r] + s1[r]) * invB : 0.f;
        }
      }
      *(f32x4*)&Wg[(size_t)q1 * SEQ + k0] = pvB;
      bf16x4 pb;
      #pragma unroll
      for (int r = 0; r < 4; ++r) pb[r] = (__bf16)pvB[r];
      *(bf16x4*)&Plds[w][1][lrow][nt * 16 + g * 4] = pb;
    }
    // PV from LDS (in-wave RAW, hardware lgkmcnt ordering; no barrier)
    #pragma unroll
    for (int kc = 0; kc < 2; ++kc) {
      bf16x8 awA, awB;
      if (liveA) awA = ld8(&Plds[w][0][lrow][kc * 32 + lk8]);
      awB = ld8(&Plds[w][1][lrow][kc * 32 + lk8]);
      #pragma unroll
      for (int nt = 0; nt < 4; ++nt) {
        const bf16x8 bv =
            ld8(Vh + (size_t)(nt * 16 + lrow) * SEQ + kb + kc * 32 + lk8);
        if (liveA) accA[nt] = mfma16(awA, bv, accA[nt]);
        accB[nt] = mfma16(awB, bv, accB[nt]);
      }
    }
  }

  #pragma unroll
  for (int nt = 0; nt < 4; ++nt)
    #pragma unroll
    for (int r = 0; r < 4; ++r) {
      unsafeAtomicAdd(
          &AOf[(size_t)(bb * SEQ + fb0 + g * 4 + r) * DIM + hh * HDIM + nt * 16 + lrow],
          accA[nt][r]);
      unsafeAtomicAdd(
          &AOf[(size_t)(bb * SEQ + fb1 + g * 4 + r) * DIM + hh * HDIM + nt * 16 + lrow],
          accB[nt][r]);
    }
}

// ---------------------------------------------------------------------------
extern "C" void kernel_launch(void* const* d_in, const int* in_sizes, int n_in,
                              void* d_out, int out_size, void* d_ws, size_t ws_size,
                              hipStream_t stream) {
  const float* x  = (const float*)d_in[0];
  const float* Wq = (const float*)d_in[2];
  const float* bq = (const float*)d_in[3];
  const float* Wk = (const float*)d_in[4];
  const float* bk = (const float*)d_in[5];
  const float* Wv = (const float*)d_in[6];
  const float* bv = (const float*)d_in[7];
  const float* Wo = (const float*)d_in[8];
  const float* bo = (const float*)d_in[9];

  char* wsb = (char*)d_ws;
  __bf16* Qb   = (__bf16*)(wsb);                 // [B,H,S,HD] bf16   6 MB
  __bf16* Kb   = (__bf16*)(wsb + 6291456);       // [B,H,S,HD] bf16   6 MB
  __bf16* Vt   = (__bf16*)(wsb + 12582912);      // [B,H,HD,S] bf16   6 MB
  float*  AOf  = (float*)(wsb + 18874368);       // [B*S, D] fp32    12 MB
  float*  sums = (float*)(wsb + 31457280);       // [24,2048] fp32  0.2 MB
  __bf16* WbT  = (__bf16*)(wsb + 31653888);      // [4,768,768] bf16 4.7 MB

  float* out   = (float*)d_out;                  // [2,2048,768] fp32
  float* attnW = out + 3145728;                  // [2,12,2048,2048] fp32
  // xb parked at the head of attnW: read only by qkv_gemm, which completes
  // before attn_sums/attn_wpv overwrite the region.
  __bf16* xb   = (__bf16*)attnW;                 // [4096,768] bf16   6 MB

  prep_misc<<<2560, 256, 0, stream>>>(x, xb, AOf);
  prep_wt<<<dim3(12, 12, 4), 256, 0, stream>>>(Wq, Wk, Wv, Wo, WbT);
  qkv_gemm<<<dim3(6, 32, 3), 256, 0, stream>>>(xb, WbT, bq, bk, bv, Qb, Kb, Vt);
  attn_sums<<<864, 256, 0, stream>>>(Qb, Kb, sums, attnW);
  attn_wpv<<<960, 256, 0, stream>>>(Qb, Kb, Vt, sums, attnW, AOf);
  out_gemm<<<dim3(12, 64), 256, 0, stream>>>(AOf, WbT, bo, out);
}

// Round 16
// 263.781 us; speedup vs baseline: 1.0305x; 1.0305x over previous
//
#include <hip/hip_runtime.h>

#define DEV static __device__ __forceinline__

typedef __bf16 bf16x8 __attribute__((ext_vector_type(8)));
typedef __bf16 bf16x4 __attribute__((ext_vector_type(4)));
typedef float  f32x4  __attribute__((ext_vector_type(4)));

DEV bf16x8 ld8(const __bf16* p) { return *reinterpret_cast<const bf16x8*>(p); }

DEV f32x4 mfma16(bf16x8 a, bf16x8 b, f32x4 c) {
  return __builtin_amdgcn_mfma_f32_16x16x32_bf16(a, b, c, 0, 0, 0);
}

// B=2, S=2048, D=768, H=12, HD=64
#define SEQ 2048
#define DIM 768
#define NH  12
#define HDIM 64

// chunk decode for 128-row q-tiles: q-tile qt has 2*qt+2 k-tiles (64 cols).
DEV void decode_chunk2(int cid, int CH, int& qt, int& t0) {
  int q = 0, rem = cid;
  while (true) {
    int nc = (2 * q + 2 + CH - 1) / CH;
    if (rem < nc) break;
    rem -= nc; ++q;
  }
  qt = q; t0 = rem * CH;
}

// chunk decode for 256-row super-tiles, CH=4: super-tile st has 4*st+4
// k-tiles -> st+1 chunks of 4.
DEV void decode_chunk4(int cid, int& st, int& t0) {
  int q = 0, rem = cid;
  while (rem >= q + 1) { rem -= q + 1; ++q; }
  st = q; t0 = rem * 4;
}

// ---------------------------------------------------------------------------
// prep_misc: fused zero(AOf+sums) and cvt(x->bf16). grid 2560 x 256.
// ---------------------------------------------------------------------------
__global__ __launch_bounds__(256) void prep_misc(const float* __restrict__ x,
                                                 __bf16* __restrict__ xb,
                                                 float* __restrict__ zp) {
  const int bid = blockIdx.x, tid = threadIdx.x;
  if (bid < 1024) {
    const int n4 = (3145728 + 49152) / 4;
    const f32x4 zv = {0.f, 0.f, 0.f, 0.f};
    for (int i = bid * 256 + tid; i < n4; i += 1024 * 256) ((f32x4*)zp)[i] = zv;
  } else {
    const int i = ((bid - 1024) * 256 + tid) * 8;
    f32x4 a = *(const f32x4*)(x + i);
    f32x4 b = *(const f32x4*)(x + i + 4);
    bf16x8 v;
    #pragma unroll
    for (int j = 0; j < 4; ++j) { v[j] = (__bf16)a[j]; v[4 + j] = (__bf16)b[j]; }
    *(bf16x8*)(xb + i) = v;
  }
}

// ---------------------------------------------------------------------------
// prep_wt: transpose+convert the 4 weight matrices to bf16 [out_n][in_k].
// ---------------------------------------------------------------------------
__global__ __launch_bounds__(256) void prep_wt(
    const float* __restrict__ Wq, const float* __restrict__ Wk,
    const float* __restrict__ Wv, const float* __restrict__ Wo,
    __bf16* __restrict__ WbT) {
  __shared__ float T[64][65];
  const int z = blockIdx.z;
  const float* W = (z == 0) ? Wq : (z == 1) ? Wk : (z == 2) ? Wv : Wo;
  const int kb = blockIdx.x * 64, nb = blockIdx.y * 64;
  const int t = threadIdx.x, r = t >> 2, c4 = (t & 3) * 16;
  #pragma unroll
  for (int j = 0; j < 16; j += 4) {
    f32x4 v = *(const f32x4*)(W + (size_t)(kb + r) * DIM + nb + c4 + j);
    T[r][c4 + j]     = v[0]; T[r][c4 + j + 1] = v[1];
    T[r][c4 + j + 2] = v[2]; T[r][c4 + j + 3] = v[3];
  }
  __syncthreads();
  bf16x8 o0, o1;
  #pragma unroll
  for (int j = 0; j < 8; ++j) {
    o0[j] = (__bf16)T[c4 + j][r];
    o1[j] = (__bf16)T[c4 + 8 + j][r];
  }
  __bf16* dst = WbT + (size_t)z * DIM * DIM + (size_t)(nb + r) * DIM + kb + c4;
  *(bf16x8*)dst = o0;
  *(bf16x8*)(dst + 8) = o1;
}

// ---------------------------------------------------------------------------
// gemm128: C[128x128 tile], 4 waves 2x2, each 64x64 via 4x4 frags, BK=64.
// LDS rows padded to 72 bf16 (144B stride) -> 2-way max bank aliasing.
// ---------------------------------------------------------------------------
DEV void gemm128(const __bf16* __restrict__ Ab, const __bf16* __restrict__ Bt,
                 const float* __restrict__ bias, void* __restrict__ outp,
                 const int mode, const float scale,
                 const int mbase, const int nbase) {
  __shared__ __bf16 As[128][72];
  __shared__ __bf16 Bs[128][72];

  const int tid  = threadIdx.x;
  const int l    = tid & 63;
  const int w    = tid >> 6;
  const int lrow = l & 15;
  const int lk8  = (l >> 4) * 8;
  const int wr = (w >> 1) * 64, wc = (w & 1) * 64;

  f32x4 acc[4][4] = {};

  const int srow = tid >> 1;          // 0..127
  const int scol = (tid & 1) * 32;    // 0 or 32 (bf16 elems)

  for (int kk = 0; kk < DIM; kk += 64) {
    {
      const __bf16* a = Ab + (size_t)(mbase + srow) * DIM + kk + scol;
      *(bf16x8*)&As[srow][scol]      = ld8(a);
      *(bf16x8*)&As[srow][scol + 8]  = ld8(a + 8);
      *(bf16x8*)&As[srow][scol + 16] = ld8(a + 16);
      *(bf16x8*)&As[srow][scol + 24] = ld8(a + 24);
    }
    {
      const __bf16* b = Bt + (size_t)(nbase + srow) * DIM + kk + scol;
      *(bf16x8*)&Bs[srow][scol]      = ld8(b);
      *(bf16x8*)&Bs[srow][scol + 8]  = ld8(b + 8);
      *(bf16x8*)&Bs[srow][scol + 16] = ld8(b + 16);
      *(bf16x8*)&Bs[srow][scol + 24] = ld8(b + 24);
    }
    __syncthreads();
    #pragma unroll
    for (int kc = 0; kc < 2; ++kc) {
      bf16x8 af[4], bf[4];
      #pragma unroll
      for (int mi = 0; mi < 4; ++mi)
        af[mi] = ld8(&As[wr + mi * 16 + lrow][kc * 32 + lk8]);
      #pragma unroll
      for (int ni = 0; ni < 4; ++ni)
        bf[ni] = ld8(&Bs[wc + ni * 16 + lrow][kc * 32 + lk8]);
      #pragma unroll
      for (int mi = 0; mi < 4; ++mi)
        #pragma unroll
        for (int ni = 0; ni < 4; ++ni)
          acc[mi][ni] = mfma16(af[mi], bf[ni], acc[mi][ni]);
    }
    __syncthreads();
  }

  #pragma unroll
  for (int mi = 0; mi < 4; ++mi)
  #pragma unroll
  for (int ni = 0; ni < 4; ++ni) {
    const int n  = nbase + wc + ni * 16 + lrow;
    const float bn = bias[n];
    const int hh = n >> 6, hd = n & 63;
    #pragma unroll
    for (int r = 0; r < 4; ++r) {
      const int m = mbase + wr + mi * 16 + (l >> 4) * 4 + r;
      const float v = (acc[mi][ni][r] + bn) * scale;
      const int bb = m >> 11, s = m & (SEQ - 1);
      if (mode == 0) {
        ((__bf16*)outp)[(((size_t)(bb * NH + hh) * SEQ) + s) * HDIM + hd] = (__bf16)v;
      } else {
        ((__bf16*)outp)[(((size_t)(bb * NH + hh) * HDIM) + hd) * SEQ + s] = (__bf16)v;
      }
    }
  }
}

__global__ __launch_bounds__(256, 2) void qkv_gemm(
    const __bf16* __restrict__ xb, const __bf16* __restrict__ WbT,
    const float* __restrict__ bq, const float* __restrict__ bk,
    const float* __restrict__ bv,
    __bf16* __restrict__ Qb, __bf16* __restrict__ Kb, __bf16* __restrict__ Vt) {
  const int z = blockIdx.z;
  const __bf16* Bt = WbT + (size_t)z * DIM * DIM;
  const float* bs = (z == 0) ? bq : (z == 1) ? bk : bv;
  void* o = (z == 0) ? (void*)Qb : (z == 1) ? (void*)Kb : (void*)Vt;
  const float sc = (z == 0) ? 0.125f : 1.f;  // fold 1/sqrt(HD) into Q
  gemm128(xb, Bt, bs, o, (z == 2) ? 1 : 0, sc,
          blockIdx.y * 128, blockIdx.x * 128);
}

// ---------------------------------------------------------------------------
// out_gemm: 64x64-tile GEMM, fp32 A (AOf), fp32 out. grid (12,64).
// ---------------------------------------------------------------------------
__global__ __launch_bounds__(256, 4) void out_gemm(
    const float* __restrict__ Af, const __bf16* __restrict__ WbT,
    const float* __restrict__ bias, float* __restrict__ out) {
  __shared__ __bf16 As[64][72];
  __shared__ __bf16 Bs[64][72];

  const __bf16* Bt = WbT + (size_t)3 * DIM * DIM;
  const int mbase = blockIdx.y * 64, nbase = blockIdx.x * 64;
  const int tid  = threadIdx.x;
  const int l    = tid & 63;
  const int w    = tid >> 6;
  const int lrow = l & 15;
  const int lk8  = (l >> 4) * 8;
  const int wrow = (w >> 1) * 32, wcol = (w & 1) * 32;

  f32x4 acc[2][2] = {};

  const int arow = tid >> 2;
  const int acol = (tid & 3) * 16;

  for (int kk = 0; kk < DIM; kk += 64) {
    {
      const float* src = Af + (size_t)(mbase + arow) * DIM + kk + acol;
      f32x4 f0 = *(const f32x4*)(src);
      f32x4 f1 = *(const f32x4*)(src + 4);
      f32x4 f2 = *(const f32x4*)(src + 8);
      f32x4 f3 = *(const f32x4*)(src + 12);
      bf16x8 v0, v1;
      #pragma unroll
      for (int j = 0; j < 4; ++j) {
        v0[j] = (__bf16)f0[j]; v0[4 + j] = (__bf16)f1[j];
        v1[j] = (__bf16)f2[j]; v1[4 + j] = (__bf16)f3[j];
      }
      *(bf16x8*)&As[arow][acol]     = v0;
      *(bf16x8*)&As[arow][acol + 8] = v1;
    }
    {
      const __bf16* bsrc = Bt + (size_t)(nbase + arow) * DIM + kk + acol;
      *(bf16x8*)&Bs[arow][acol]     = ld8(bsrc);
      *(bf16x8*)&Bs[arow][acol + 8] = ld8(bsrc + 8);
    }
    __syncthreads();
    #pragma unroll
    for (int kc = 0; kc < 2; ++kc) {
      bf16x8 a0 = ld8(&As[wrow + lrow][kc * 32 + lk8]);
      bf16x8 a1 = ld8(&As[wrow + 16 + lrow][kc * 32 + lk8]);
      bf16x8 b0 = ld8(&Bs[wcol + lrow][kc * 32 + lk8]);
      bf16x8 b1 = ld8(&Bs[wcol + 16 + lrow][kc * 32 + lk8]);
      acc[0][0] = mfma16(a0, b0, acc[0][0]);
      acc[0][1] = mfma16(a0, b1, acc[0][1]);
      acc[1][0] = mfma16(a1, b0, acc[1][0]);
      acc[1][1] = mfma16(a1, b1, acc[1][1]);
    }
    __syncthreads();
  }

  #pragma unroll
  for (int mi = 0; mi < 2; ++mi)
  #pragma unroll
  for (int ni = 0; ni < 2; ++ni) {
    const int n  = nbase + wcol + ni * 16 + lrow;
    const float bn = bias[n];
    #pragma unroll
    for (int r = 0; r < 4; ++r) {
      const int m = mbase + wrow + mi * 16 + (l >> 4) * 4 + r;
      out[(size_t)m * DIM + n] = acc[mi][ni][r] + bn;
    }
  }
}

// ---------------------------------------------------------------------------
// attn_sums: swapped-operand QK^T, 4 q-frags/wave over 256-row super-tiles.
// setprio(1) around the MFMA cluster (T5: helps independent-wave attn
// structures, m191). Fused zero-fill incl. half-width hole strip.
// grid = 8*3*36 = 864 blocks.
// ---------------------------------------------------------------------------
__global__ __launch_bounds__(256, 4) void attn_sums(
    const __bf16* __restrict__ Q, const __bf16* __restrict__ K,
    float* __restrict__ sums, float* __restrict__ Wout) {
  const int tid = threadIdx.x, l = tid & 63, w = tid >> 6;
  const int lrow = l & 15, lk8 = (l >> 4) * 8, g = l >> 4;
  const int lin = blockIdx.x;
  const int C = 36;
  const int bh = (lin & 7) * 3 + (lin >> 3) / C;
  const int cid = (lin >> 3) % C;
  int st, t0; decode_chunk4(cid, st, t0);
  const int tmax = 4 * st + 4;
  const int t1 = (t0 + 4 < tmax) ? t0 + 4 : tmax;

  const __bf16* Qh = Q + (size_t)bh * SEQ * HDIM;
  const __bf16* Kh = K + (size_t)bh * SEQ * HDIM;

  int fb[4];
  bf16x8 bq0[4], bq1[4];
  #pragma unroll
  for (int i = 0; i < 4; ++i) {
    fb[i] = st * 256 + w * 64 + i * 16;
    const int q = fb[i] + lrow;
    bq0[i] = ld8(Qh + (size_t)q * HDIM + lk8);
    bq1[i] = ld8(Qh + (size_t)q * HDIM + 32 + lk8);
  }

  float ssum[4] = {0.f, 0.f, 0.f, 0.f};
  for (int t = t0; t < t1; ++t) {
    const int kb = t * 64;
    if (kb > fb[3] + 15) continue;  // above all 4 frags
    #pragma unroll
    for (int nt = 0; nt < 4; ++nt) {
      const int krow = kb + nt * 16 + lrow;
      const bf16x8 ak0 = ld8(Kh + (size_t)krow * HDIM + lk8);
      const bf16x8 ak1 = ld8(Kh + (size_t)krow * HDIM + 32 + lk8);
      const int k0 = kb + nt * 16 + g * 4;
      #pragma unroll
      for (int i = 0; i < 4; ++i) {
        if (kb <= fb[i] + 15) {  // frag live (wave-uniform)
          f32x4 s0 = {0.f, 0.f, 0.f, 0.f}, s1 = {0.f, 0.f, 0.f, 0.f};
          __builtin_amdgcn_s_setprio(1);
          s0 = mfma16(ak0, bq0[i], s0);
          s1 = mfma16(ak1, bq1[i], s1);
          __builtin_amdgcn_s_setprio(0);
          const int q = fb[i] + lrow;
          if (kb + 63 <= fb[i]) {
            #pragma unroll
            for (int r = 0; r < 4; ++r) ssum[i] += __expf(s0[r] + s1[r]);
          } else {
            #pragma unroll
            for (int r = 0; r < 4; ++r)
              ssum[i] += (k0 + r <= q) ? __expf(s0[r] + s1[r]) : 0.f;
          }
        }
      }
    }
  }
  #pragma unroll
  for (int i = 0; i < 4; ++i) {
    ssum[i] += __shfl_xor(ssum[i], 16);
    ssum[i] += __shfl_xor(ssum[i], 32);
  }
  if (g == 0) {
    #pragma unroll
    for (int i = 0; i < 4; ++i)
      unsafeAtomicAdd(&sums[bh * SEQ + fb[i] + lrow], ssum[i]);
  }

  float* Wg = Wout + (size_t)bh * SEQ * SEQ;
  const f32x4 zv = {0.f, 0.f, 0.f, 0.f};
  // ---- full-width reflected fill: t in [t0, min(t1, 4*st)) ----
  const int tz = (t1 < 4 * st) ? t1 : 4 * st;
  if (t0 < tz) {
    const int zr = tid >> 2;             // 0..63
    const int zc = (tid & 3) * 64;       // 0,64,128,192 floats
    for (int t = t0; t < tz; ++t) {
      float* base = Wg + (size_t)(t * 64 + zr) * SEQ + st * 256 + zc;
      #pragma unroll
      for (int c = 0; c < 16; ++c) *(f32x4*)(base + c * 4) = zv;
    }
  }
  // ---- half-width hole fill: t in [max(t0,4st), min(t1,4st+2)),
  //      cols [st*256+128, st*256+256) (wpv qt=2st stops at col 256st+128) --
  const int ta = (t0 > 4 * st) ? t0 : 4 * st;
  const int tb = (t1 < 4 * st + 2) ? t1 : 4 * st + 2;
  if (ta < tb) {
    const int zr = tid >> 2;
    const int zc = (tid & 3) * 32;       // 0,32,64,96 floats (128 total)
    for (int t = ta; t < tb; ++t) {
      float* base = Wg + (size_t)(t * 64 + zr) * SEQ + st * 256 + 128 + zc;
      #pragma unroll
      for (int c = 0; c < 8; ++c) *(f32x4*)(base + c * 4) = zv;
    }
  }
}

// ---------------------------------------------------------------------------
// attn_wpv: swapped-operand QK^T, 2 q-frags/wave; f32x4 Wg stores direct from
// registers; bf16 P staged to LDS (in-wave RAW, no barriers); setprio(1)
// around MFMA clusters (T5). atomicAdd AOf. grid = 8*3*40 = 960 blocks.
// ---------------------------------------------------------------------------
__global__ __launch_bounds__(256, 4) void attn_wpv(
    const __bf16* __restrict__ Q, const __bf16* __restrict__ K,
    const __bf16* __restrict__ VT, const float* __restrict__ sums,
    float* __restrict__ Wout, float* __restrict__ AOf) {
  __shared__ __bf16 Plds[4][2][16][72];

  const int tid = threadIdx.x, l = tid & 63, w = tid >> 6;
  const int lrow = l & 15, lk8 = (l >> 4) * 8, g = l >> 4;
  const int lin = blockIdx.x;
  const int C = 40;
  const int bh = (lin & 7) * 3 + (lin >> 3) / C;
  const int cid = (lin >> 3) % C;
  int qt, t0; decode_chunk2(cid, 8, qt, t0);
  const int tmax = 2 * qt + 2;
  const int t1 = (t0 + 8 < tmax) ? t0 + 8 : tmax;
  const int bb = bh / NH, hh = bh % NH;
  const int fb0 = qt * 128 + w * 32;
  const int fb1 = fb0 + 16;
  const int q0 = fb0 + lrow, q1 = fb1 + lrow;

  const __bf16* Qh = Q + (size_t)bh * SEQ * HDIM;
  const __bf16* Kh = K + (size_t)bh * SEQ * HDIM;
  const __bf16* Vh = VT + (size_t)bh * HDIM * SEQ;
  float* Wg = Wout + (size_t)bh * SEQ * SEQ;

  const bf16x8 bqA0 = ld8(Qh + (size_t)q0 * HDIM + lk8);
  const bf16x8 bqA1 = ld8(Qh + (size_t)q0 * HDIM + 32 + lk8);
  const bf16x8 bqB0 = ld8(Qh + (size_t)q1 * HDIM + lk8);
  const bf16x8 bqB1 = ld8(Qh + (size_t)q1 * HDIM + 32 + lk8);
  const float invA = 1.f / sums[bh * SEQ + q0];
  const float invB = 1.f / sums[bh * SEQ + q1];

  f32x4 accA[4] = {}, accB[4] = {};
  for (int t = t0; t < t1; ++t) {
    const int kb = t * 64;
    const bool liveA = (kb <= fb0 + 15);
    const bool liveB = (kb <= fb1 + 15);
    const f32x4 zv = {0.f, 0.f, 0.f, 0.f};
    if (!liveB) {
      #pragma unroll
      for (int nt = 0; nt < 4; ++nt) {
        const int k0 = kb + nt * 16 + g * 4;
        *(f32x4*)&Wg[(size_t)q0 * SEQ + k0] = zv;
        *(f32x4*)&Wg[(size_t)q1 * SEQ + k0] = zv;
      }
      continue;
    }
    #pragma unroll
    for (int nt = 0; nt < 4; ++nt) {
      const int krow = kb + nt * 16 + lrow;
      const bf16x8 ak0 = ld8(Kh + (size_t)krow * HDIM + lk8);
      const bf16x8 ak1 = ld8(Kh + (size_t)krow * HDIM + 32 + lk8);
      const int k0 = kb + nt * 16 + g * 4;
      f32x4 pvA = zv;
      if (liveA) {
        f32x4 s0 = {0.f, 0.f, 0.f, 0.f}, s1 = {0.f, 0.f, 0.f, 0.f};
        __builtin_amdgcn_s_setprio(1);
        s0 = mfma16(ak0, bqA0, s0);
        s1 = mfma16(ak1, bqA1, s1);
        __builtin_amdgcn_s_setprio(0);
        if (kb + 63 <= fb0) {
          #pragma unroll
          for (int r = 0; r < 4; ++r) pvA[r] = __expf(s0[r] + s1[r]) * invA;
        } else {
          #pragma unroll
          for (int r = 0; r < 4; ++r)
            pvA[r] = (k0 + r <= q0) ? __expf(s0[r] + s1[r]) * invA : 0.f;
        }
        bf16x4 pb;
        #pragma unroll
        for (int r = 0; r < 4; ++r) pb[r] = (__bf16)pvA[r];
        *(bf16x4*)&Plds[w][0][lrow][nt * 16 + g * 4] = pb;
      }
      *(f32x4*)&Wg[(size_t)q0 * SEQ + k0] = pvA;
      f32x4 pvB;
      {
        f32x4 s0 = {0.f, 0.f, 0.f, 0.f}, s1 = {0.f, 0.f, 0.f, 0.f};
        __builtin_amdgcn_s_setprio(1);
        s0 = mfma16(ak0, bqB0, s0);
        s1 = mfma16(ak1, bqB1, s1);
        __builtin_amdgcn_s_setprio(0);
        if (kb + 63 <= fb1) {
          #pragma unroll
          for (int r = 0; r < 4; ++r) pvB[r] = __expf(s0[r] + s1[r]) * invB;
        } else {
          #pragma unroll
          for (int r = 0; r < 4; ++r)
            pvB[r] = (k0 + r <= q1) ? __expf(s0[r] + s1[r]) * invB : 0.f;
        }
      }
      *(f32x4*)&Wg[(size_t)q1 * SEQ + k0] = pvB;
      bf16x4 pb;
      #pragma unroll
      for (int r = 0; r < 4; ++r) pb[r] = (__bf16)pvB[r];
      *(bf16x4*)&Plds[w][1][lrow][nt * 16 + g * 4] = pb;
    }
    // PV from LDS (in-wave RAW, hardware lgkmcnt ordering; no barrier)
    #pragma unroll
    for (int kc = 0; kc < 2; ++kc) {
      bf16x8 awA, awB;
      if (liveA) awA = ld8(&Plds[w][0][lrow][kc * 32 + lk8]);
      awB = ld8(&Plds[w][1][lrow][kc * 32 + lk8]);
      __builtin_amdgcn_s_setprio(1);
      #pragma unroll
      for (int nt = 0; nt < 4; ++nt) {
        const bf16x8 bv =
            ld8(Vh + (size_t)(nt * 16 + lrow) * SEQ + kb + kc * 32 + lk8);
        if (liveA) accA[nt] = mfma16(awA, bv, accA[nt]);
        accB[nt] = mfma16(awB, bv, accB[nt]);
      }
      __builtin_amdgcn_s_setprio(0);
    }
  }

  #pragma unroll
  for (int nt = 0; nt < 4; ++nt)
    #pragma unroll
    for (int r = 0; r < 4; ++r) {
      unsafeAtomicAdd(
          &AOf[(size_t)(bb * SEQ + fb0 + g * 4 + r) * DIM + hh * HDIM + nt * 16 + lrow],
          accA[nt][r]);
      unsafeAtomicAdd(
          &AOf[(size_t)(bb * SEQ + fb1 + g * 4 + r) * DIM + hh * HDIM + nt * 16 + lrow],
          accB[nt][r]);
    }
}

// ---------------------------------------------------------------------------
extern "C" void kernel_launch(void* const* d_in, const int* in_sizes, int n_in,
                              void* d_out, int out_size, void* d_ws, size_t ws_size,
                              hipStream_t stream) {
  const float* x  = (const float*)d_in[0];
  const float* Wq = (const float*)d_in[2];
  const float* bq = (const float*)d_in[3];
  const float* Wk = (const float*)d_in[4];
  const float* bk = (const float*)d_in[5];
  const float* Wv = (const float*)d_in[6];
  const float* bv = (const float*)d_in[7];
  const float* Wo = (const float*)d_in[8];
  const float* bo = (const float*)d_in[9];

  char* wsb = (char*)d_ws;
  __bf16* Qb   = (__bf16*)(wsb);                 // [B,H,S,HD] bf16   6 MB
  __bf16* Kb   = (__bf16*)(wsb + 6291456);       // [B,H,S,HD] bf16   6 MB
  __bf16* Vt   = (__bf16*)(wsb + 12582912);      // [B,H,HD,S] bf16   6 MB
  float*  AOf  = (float*)(wsb + 18874368);       // [B*S, D] fp32    12 MB
  float*  sums = (float*)(wsb + 31457280);       // [24,2048] fp32  0.2 MB
  __bf16* WbT  = (__bf16*)(wsb + 31653888);      // [4,768,768] bf16 4.7 MB

  float* out   = (float*)d_out;                  // [2,2048,768] fp32
  float* attnW = out + 3145728;                  // [2,12,2048,2048] fp32
  // xb parked at the head of attnW: read only by qkv_gemm, which completes
  // before attn_sums/attn_wpv overwrite the region.
  __bf16* xb   = (__bf16*)attnW;                 // [4096,768] bf16   6 MB

  prep_misc<<<2560, 256, 0, stream>>>(x, xb, AOf);
  prep_wt<<<dim3(12, 12, 4), 256, 0, stream>>>(Wq, Wk, Wv, Wo, WbT);
  qkv_gemm<<<dim3(6, 32, 3), 256, 0, stream>>>(xb, WbT, bq, bk, bv, Qb, Kb, Vt);
  attn_sums<<<864, 256, 0, stream>>>(Qb, Kb, sums, attnW);
  attn_wpv<<<960, 256, 0, stream>>>(Qb, Kb, Vt, sums, attnW, AOf);
  out_gemm<<<dim3(12, 64), 256, 0, stream>>>(AOf, WbT, bo, out);
}